// Round 3
// baseline (206.492 us; speedup 1.0000x reference)
//
#include <hip/hip_runtime.h>

// ---------------------------------------------------------------------------
// DiffusionModel — algebraically collapsed implementation (round 2 resubmit;
// round-2 bench failed on a full compile-node disk, not a kernel issue).
//
//   eq_hidden == 0 always  => gate/mix/W_gate/W_mix dead, project = b_proj.
//   pred[s,n,c] = xt[s,n,c]*D1[s,n] + D2[s,n]
//     D1 = w1·u + c1,  D2 = w2·u + c2   (w1,w2,c1,c2 precomputed)
//   u = tanh(W_rec[:, :H] @ hp + b_rec),  hp = W_in @ h[j0] + b_in
//   D1/D2 depend only on node j0 => compute per NODE (50k), gather per pair.
//
// Node kernel tiling: 64 nodes per block x 4 waves, row-split phases with an
// LDS hp round-trip (3128 waves total, ~3 waves/SIMD vs 0.76 in round 1).
// ---------------------------------------------------------------------------

constexpr int N_NODES = 50000;
constexpr int F_IN    = 64;
constexpr int H       = 128;
constexpr int S_WALKS = 4;
constexpr int STEPS   = 100;

// workspace layout (float offsets)
constexpr int WS_WINT = 0;                    // W_in transposed: [64][128]
constexpr int WS_W1   = WS_WINT + F_IN * H;   // 8192
constexpr int WS_W2   = WS_W1 + H;            // 8320
constexpr int WS_SC   = WS_W2 + H;            // 8448: sa, sb, c1, c2
constexpr int WS_D12  = WS_SC + 8;            // 8456: interleaved d1,d2 per node
constexpr int WS_PART = WS_D12 + 2 * N_NODES; // 108456: per-wave partials
constexpr int LOSS_BLOCKS = (S_WALKS * N_NODES + 255) / 256; // 782
constexpr int NPART   = LOSS_BLOCKS * 4;      // 4 waves per 256-thread block

// ---------------------------------------------------------------------------
// K1: tiny precompute. 1 block, 128 threads.
// ---------------------------------------------------------------------------
__global__ void precompute_kernel(const float* __restrict__ W_in,
                                  const float* __restrict__ W_damp,
                                  const float* __restrict__ b_damp,
                                  const float* __restrict__ b_proj,
                                  const int* __restrict__ t_idx_p,
                                  float* ws) {
  const int t = threadIdx.x; // 128 threads

  // transpose W_in:  WinT[k*H + r] = W_in[r*F_IN + k]
  for (int idx = t; idx < H * F_IN; idx += 128) {
    int r = idx / F_IN, k = idx % F_IN;
    ws[WS_WINT + k * H + r] = W_in[idx];
  }

  const int   ti   = *t_idx_p;
  const float tval = (float)ti / (float)STEPS;
  const float ct = cosf(tval), st = sinf(tval);

  // w1[k] = mean_h W_damp[h][k];  w2[k] = mean_h b_proj[h]*W_damp[h][k]
  if (t < H) {
    float s1 = 0.f, s2 = 0.f;
    for (int h = 0; h < H; ++h) {
      float v = W_damp[h * (H + 2) + t];
      s1 += v;
      s2 += b_proj[h] * v;
    }
    ws[WS_W1 + t] = s1 * (1.0f / H);
    ws[WS_W2 + t] = s2 * (1.0f / H);
  }

  // c1 = mean_h c_damp[h];  c2 = mean_h b_proj[h]*c_damp[h]
  __shared__ float red1[128], red2[128];
  float cd = 0.f, cd2 = 0.f;
  if (t < H) {
    float c = b_damp[t] + W_damp[t * (H + 2) + H] * ct
                        + W_damp[t * (H + 2) + H + 1] * st;
    cd = c;
    cd2 = b_proj[t] * c;
  }
  red1[t] = cd;
  red2[t] = cd2;
  __syncthreads();
  if (t == 0) {
    float s1 = 0.f, s2 = 0.f;
    for (int i = 0; i < H; ++i) { s1 += red1[i]; s2 += red2[i]; }
    ws[WS_SC + 2] = s1 * (1.0f / H);
    ws[WS_SC + 3] = s2 * (1.0f / H);
    // alpha_bar = cumprod(1 - linspace(1e-4, 0.02, STEPS))[t_idx]
    float ab = 1.0f;
    const float step = (0.02f - 0.0001f) / (float)(STEPS - 1);
    for (int i = 0; i <= ti; ++i) {
      float beta = 0.0001f + step * (float)i;
      ab *= (1.0f - beta);
    }
    ws[WS_SC + 0] = sqrtf(ab);
    ws[WS_SC + 1] = sqrtf(1.0f - ab);
  }
}

// ---------------------------------------------------------------------------
// K2: 64 nodes per block, 256 threads (4 waves).
//   lane l = node within tile, wave w = row-quarter [32w, 32w+32).
//   phase 1: acc[32] = b_in + W_in @ h  -> hpT[r][l] in LDS (stride 65)
//   phase 2: per 8-row block, stream hp once, 8 fma streams; tanh; w1/w2 dots
//   reduce d1/d2 partials across the 4 waves via LDS.
// Weights are read at wave-uniform addresses (scalar/broadcast path).
// ---------------------------------------------------------------------------
__global__ __launch_bounds__(256) void node_kernel(
    const float* __restrict__ hin,
    const float* __restrict__ b_in,
    const float* __restrict__ W_rec,
    const float* __restrict__ b_rec,
    const float* __restrict__ winT,
    const float* __restrict__ w1v,
    const float* __restrict__ w2v,
    float* __restrict__ d12) {
  __shared__ float h_lds[64 * 65];
  __shared__ float hpT[128 * 65];
  __shared__ float redbuf[2 * 4 * 64];

  const int t = threadIdx.x;
  const int l = t & 63;   // node lane
  const int w = t >> 6;   // wave id (row quarter)
  const int base = blockIdx.x * 64;
  const int nvalid = N_NODES - base; // >= 16 on last block

  // stage h tile: 64 nodes x 64 feats, contiguous 16 KB, float4 coalesced
  {
    const float* src = hin + (size_t)base * F_IN;
#pragma unroll
    for (int i = 0; i < 4; ++i) {
      int idx = i * 1024 + t * 4;
      int node = idx >> 6, feat = idx & 63;
      float4 v = make_float4(0.f, 0.f, 0.f, 0.f);
      if (node < nvalid) v = *(const float4*)(src + idx);
      float* dst = &h_lds[node * 65 + feat];
      dst[0] = v.x; dst[1] = v.y; dst[2] = v.z; dst[3] = v.w;
    }
  }
  __syncthreads();

  // ---- phase 1: hp rows [32w, 32w+32) for node l
  const int r0 = w * 32;
  float acc[32];
#pragma unroll
  for (int j = 0; j < 32; ++j) acc[j] = b_in[r0 + j];

  const float* hrow = &h_lds[l * 65];
#pragma unroll 4
  for (int k = 0; k < F_IN; ++k) {
    float hk = hrow[k];
    const float* wc = winT + k * H + r0;  // wave-uniform
#pragma unroll
    for (int j = 0; j < 32; ++j) acc[j] = fmaf(wc[j], hk, acc[j]);
  }

#pragma unroll
  for (int j = 0; j < 32; ++j) hpT[(r0 + j) * 65 + l] = acc[j];
  __syncthreads();

  // ---- phase 2: u rows [32w, 32w+32); 8-row register blocking.
  // All indices below are compile-time after full unroll -> a[] stays in VGPRs.
  float d1p = 0.f, d2p = 0.f;
#pragma unroll
  for (int ib = 0; ib < 4; ++ib) {
    const int rp0 = r0 + ib * 8;
    float a[8];
#pragma unroll
    for (int q = 0; q < 8; ++q) a[q] = 0.f;
#pragma unroll 2
    for (int r = 0; r < H; r += 4) {
      float hv0 = hpT[(r + 0) * 65 + l];
      float hv1 = hpT[(r + 1) * 65 + l];
      float hv2 = hpT[(r + 2) * 65 + l];
      float hv3 = hpT[(r + 3) * 65 + l];
      const float* wb = W_rec + (size_t)rp0 * (2 * H) + r; // wave-uniform
#pragma unroll
      for (int q = 0; q < 8; ++q) {
        const float* wr = wb + q * (2 * H);
        a[q] = fmaf(wr[0], hv0, a[q]);
        a[q] = fmaf(wr[1], hv1, a[q]);
        a[q] = fmaf(wr[2], hv2, a[q]);
        a[q] = fmaf(wr[3], hv3, a[q]);
      }
    }
#pragma unroll
    for (int q = 0; q < 8; ++q) {
      float u = tanhf(a[q] + b_rec[rp0 + q]);
      d1p = fmaf(w1v[rp0 + q], u, d1p);
      d2p = fmaf(w2v[rp0 + q], u, d2p);
    }
  }

  // ---- cross-wave reduction of d1/d2 partials
  redbuf[w * 64 + l] = d1p;
  redbuf[256 + w * 64 + l] = d2p;
  __syncthreads();
  if (w == 0) {
    float d1 = redbuf[l] + redbuf[64 + l] + redbuf[128 + l] + redbuf[192 + l];
    float d2 = redbuf[256 + l] + redbuf[320 + l] + redbuf[384 + l] + redbuf[448 + l];
    const int n = base + l;
    if (n < N_NODES) {
      d12[2 * n]     = d1;
      d12[2 * n + 1] = d2;
    }
  }
}

// ---------------------------------------------------------------------------
// K3: loss gather + partial reduction. One thread per (s,n) pair.
// ---------------------------------------------------------------------------
__global__ __launch_bounds__(256) void loss_kernel(
    const float* __restrict__ x,
    const int* __restrict__ walks,
    const float* __restrict__ eps,
    const float* ws,
    float* __restrict__ partials) {
  const int idx = blockIdx.x * 256 + threadIdx.x;
  const float sa = ws[WS_SC + 0];
  const float sb = ws[WS_SC + 1];

  float local = 0.f;
  if (idx < S_WALKS * N_NODES) {
    const int j0 = walks[idx * 2];
    const int j1 = walks[idx * 2 + 1];
    const float d1 = ws[WS_D12 + 2 * j0];
    const float d2 = ws[WS_D12 + 2 * j0 + 1];
#pragma unroll
    for (int c = 0; c < 3; ++c) {
      float e  = eps[idx * 3 + c];
      float xt = fmaf(sa, x[j1 * 3 + c], sb * e);
      float diff = fmaf(xt, d1, d2) - e;
      local = fmaf(diff, diff, local);
    }
  }
  for (int off = 32; off > 0; off >>= 1)
    local += __shfl_down(local, off, 64);
  if ((threadIdx.x & 63) == 0)
    partials[blockIdx.x * 4 + (threadIdx.x >> 6)] = local;
}

// ---------------------------------------------------------------------------
// K4: finalize.
// ---------------------------------------------------------------------------
__global__ __launch_bounds__(256) void finalize_kernel(
    const float* __restrict__ partials, int np, float* __restrict__ out) {
  __shared__ float red[256];
  float s = 0.f;
  for (int i = threadIdx.x; i < np; i += 256) s += partials[i];
  red[threadIdx.x] = s;
  __syncthreads();
  for (int w = 128; w > 0; w >>= 1) {
    if (threadIdx.x < w) red[threadIdx.x] += red[threadIdx.x + w];
    __syncthreads();
  }
  if (threadIdx.x == 0)
    out[0] = red[0] * (1.0f / (float)(S_WALKS * N_NODES * 3));
}

// ---------------------------------------------------------------------------
extern "C" void kernel_launch(void* const* d_in, const int* in_sizes, int n_in,
                              void* d_out, int out_size, void* d_ws, size_t ws_size,
                              hipStream_t stream) {
  const float* h      = (const float*)d_in[0];
  const float* x      = (const float*)d_in[1];
  const int*   walks  = (const int*)d_in[2];
  const float* eps    = (const float*)d_in[3];
  const int*   t_idx  = (const int*)d_in[4];
  const float* W_in   = (const float*)d_in[5];
  const float* b_in   = (const float*)d_in[6];
  const float* W_rec  = (const float*)d_in[7];
  const float* b_rec  = (const float*)d_in[8];
  // d_in[9..12] dead (eq_hidden == 0); d_in[15] W_proj dead.
  const float* W_damp = (const float*)d_in[13];
  const float* b_damp = (const float*)d_in[14];
  const float* b_proj = (const float*)d_in[16];

  float* ws  = (float*)d_ws;
  float* out = (float*)d_out;

  hipLaunchKernelGGL(precompute_kernel, dim3(1), dim3(128), 0, stream,
                     W_in, W_damp, b_damp, b_proj, t_idx, ws);

  hipLaunchKernelGGL(node_kernel, dim3((N_NODES + 63) / 64), dim3(256), 0,
                     stream, h, b_in, W_rec, b_rec,
                     ws + WS_WINT, ws + WS_W1, ws + WS_W2,
                     ws + WS_D12);

  hipLaunchKernelGGL(loss_kernel, dim3(LOSS_BLOCKS), dim3(256), 0, stream,
                     x, walks, eps, ws, ws + WS_PART);

  hipLaunchKernelGGL(finalize_kernel, dim3(1), dim3(256), 0, stream,
                     ws + WS_PART, NPART, out);
}

// Round 5
// 111.578 us; speedup vs baseline: 1.8507x; 1.8507x over previous
//
#include <hip/hip_runtime.h>

// ---------------------------------------------------------------------------
// DiffusionModel — algebraically collapsed (round 4 resubmit; round-4 bench
// died on compile-node disk-full, not a kernel defect).
//
//   eq_hidden == 0 always  => gate/mix/W_gate/W_mix dead, project = b_proj.
//   pred[s,n,c] = xt[s,n,c]*D1[s,n] + D2[s,n]
//     D1 = w1·u + c1,  D2 = w2·u + c2   (w1,w2,c1,c2 precomputed in K1)
//   u = tanh(W_rec[:, :H] @ hp + b_rec),  hp = W_in @ h[j0] + b_in
//   D1/D2 depend only on node j0 => compute per NODE (50k), gather per pair.
//
// Weight-stationary node kernel (from round-3 counters: VALUBusy 20%,
// latency-bound on per-lane global weight loads): all weights staged in LDS
// once per block (conflict-free padded layouts), lanes = output rows,
// 8 nodes register-blocked per wave (32 FMAs per weight ds_read_b128 ->
// LDS demand ~72 B/cyc < 128 B/cyc ceiling). 1024-thread persistent blocks.
// ---------------------------------------------------------------------------

constexpr int N_NODES = 50000;
constexpr int F_IN    = 64;
constexpr int H       = 128;
constexpr int S_WALKS = 4;
constexpr int STEPS   = 100;

// workspace layout (float offsets)
constexpr int WS_W1   = 0;                    // w1[128]
constexpr int WS_W2   = WS_W1 + H;            // w2[128]
constexpr int WS_SC   = WS_W2 + H;            // sa, sb, c1, c2
constexpr int WS_D12  = WS_SC + 8;            // interleaved d1,d2 per node
constexpr int WS_PART = WS_D12 + 2 * N_NODES; // per-wave loss partials
constexpr int LOSS_BLOCKS = (S_WALKS * N_NODES + 255) / 256; // 782
constexpr int NPART   = LOSS_BLOCKS * 4;

// node kernel geometry
constexpr int TILE      = 64;                          // nodes per tile
constexpr int N_TILES   = (N_NODES + TILE - 1) / TILE; // 782
constexpr int NODE_GRID = 256;                         // persistent blocks

// node-kernel LDS carve (float offsets). Row strides 132/68 are ≡4 (mod 32)
// words and 16B-aligned => per-lane-row ds_read_b128 hits the 8-words/bank
// minimum (no excess conflicts).
constexpr int L_WREC  = 0;                   // [128][132] W_rec[:, :128]
constexpr int L_WIN   = L_WREC + 128 * 132;  // [128][68]  W_in
constexpr int L_H     = L_WIN + 128 * 68;    // [64][64]   h tile
constexpr int L_HP    = L_H + 64 * 64;       // [64][128]  hp tile
constexpr int L_BIN   = L_HP + 64 * 128;     // b_in[128]
constexpr int L_BREC  = L_BIN + 128;         // b_rec[128]
constexpr int L_V1    = L_BREC + 128;        // w1[128]
constexpr int L_V2    = L_V1 + 128;          // w2[128]
constexpr int L_RED   = L_V2 + 128;          // [64 nodes][2 g][2 c]
constexpr int L_TOTAL = L_RED + 256;         // 38656 floats = 154,624 B
constexpr size_t NODE_LDS_BYTES = (size_t)L_TOTAL * 4;

// ---------------------------------------------------------------------------
// K1: tiny precompute (w1, w2, c1, c2, sa, sb). 1 block, 128 threads.
// ---------------------------------------------------------------------------
__global__ void precompute_kernel(const float* __restrict__ W_damp,
                                  const float* __restrict__ b_damp,
                                  const float* __restrict__ b_proj,
                                  const int* __restrict__ t_idx_p,
                                  float* ws) {
  const int t = threadIdx.x; // 128 threads

  const int   ti   = *t_idx_p;
  const float tval = (float)ti / (float)STEPS;
  const float ct = cosf(tval), st = sinf(tval);

  // w1[k] = mean_h W_damp[h][k];  w2[k] = mean_h b_proj[h]*W_damp[h][k]
  float s1 = 0.f, s2 = 0.f;
  for (int hh = 0; hh < H; ++hh) {
    float v = W_damp[hh * (H + 2) + t];
    s1 += v;
    s2 += b_proj[hh] * v;
  }
  ws[WS_W1 + t] = s1 * (1.0f / H);
  ws[WS_W2 + t] = s2 * (1.0f / H);

  // c1 = mean_h c_damp[h];  c2 = mean_h b_proj[h]*c_damp[h]
  __shared__ float red1[128], red2[128];
  {
    float c = b_damp[t] + W_damp[t * (H + 2) + H] * ct
                        + W_damp[t * (H + 2) + H + 1] * st;
    red1[t] = c;
    red2[t] = b_proj[t] * c;
  }
  __syncthreads();
  if (t == 0) {
    float a1 = 0.f, a2 = 0.f;
    for (int i = 0; i < H; ++i) { a1 += red1[i]; a2 += red2[i]; }
    ws[WS_SC + 2] = a1 * (1.0f / H);
    ws[WS_SC + 3] = a2 * (1.0f / H);
    float ab = 1.0f;
    const float step = (0.02f - 0.0001f) / (float)(STEPS - 1);
    for (int i = 0; i <= ti; ++i) {
      float beta = 0.0001f + step * (float)i;
      ab *= (1.0f - beta);
    }
    ws[WS_SC + 0] = sqrtf(ab);
    ws[WS_SC + 1] = sqrtf(1.0f - ab);
  }
}

// ---------------------------------------------------------------------------
// K2: weight-stationary node kernel.
//   1024 threads = 16 waves. wave W: o = W&7 (node octet), g = W>>3 (row half).
//   lane l owns row r = g*64 + l. Weights from LDS (staged once), h/hp
//   broadcasts from LDS. 8-node register blocking: 32 FMAs per weight b128.
// ---------------------------------------------------------------------------
__global__ __launch_bounds__(1024, 4) void node_kernel(
    const float* __restrict__ hin,
    const float* __restrict__ W_in,
    const float* __restrict__ b_in,
    const float* __restrict__ W_rec,
    const float* __restrict__ b_rec,
    float* __restrict__ ws) {
  extern __shared__ float sm[];
  const int t = threadIdx.x;
  const int l = t & 63;
  const int Wv = t >> 6;
  const int o = Wv & 7;       // node octet within tile
  const int g = Wv >> 3;      // row half
  const int r = g * 64 + l;   // this lane's output row

  float* d12 = ws + WS_D12;
  const float C1 = ws[WS_SC + 2];
  const float C2 = ws[WS_SC + 3];

  // ---- stage weights + vectors once per block (coalesced float4 -> LDS)
#pragma unroll
  for (int i = 0; i < 2; ++i) {            // W_in: 128x64 = 2048 float4
    int idx = t + i * 1024;
    int row = idx >> 4, cc = idx & 15;
    float4 v = *(const float4*)(W_in + row * 64 + cc * 4);
    *(float4*)(sm + L_WIN + row * 68 + cc * 4) = v;
  }
#pragma unroll
  for (int i = 0; i < 4; ++i) {            // W_rec[:, :128]: 4096 float4
    int idx = t + i * 1024;
    int row = idx >> 5, cc = idx & 31;
    float4 v = *(const float4*)(W_rec + row * 256 + cc * 4);
    *(float4*)(sm + L_WREC + row * 132 + cc * 4) = v;
  }
  if (t < 128) {
    sm[L_BIN + t]  = b_in[t];
    sm[L_BREC + t] = b_rec[t];
    sm[L_V1 + t]   = ws[WS_W1 + t];
    sm[L_V2 + t]   = ws[WS_W2 + t];
  }

  // ---- persistent loop over 64-node tiles
  for (int tile = blockIdx.x; tile < N_TILES; tile += NODE_GRID) {
    const int base = tile * TILE;
    __syncthreads();   // weights staged / previous tile fully consumed

    // stage h tile: 64 nodes x 64 feats (zero-fill invalid nodes)
    {
      int node = t >> 4, cc = t & 15;
      float4 v = make_float4(0.f, 0.f, 0.f, 0.f);
      if (base + node < N_NODES)
        v = *(const float4*)(hin + (size_t)(base + node) * F_IN + cc * 4);
      *(float4*)(sm + L_H + node * 64 + cc * 4) = v;
    }
    __syncthreads();

    // ---- GEMM1: hp[n][r] = b_in[r] + sum_k W_in[r][k] h[n][k], octet o
    {
      float a[8];
#pragma unroll
      for (int j = 0; j < 8; ++j) a[j] = 0.f;
      const float* wrow  = sm + L_WIN + r * 68;
      const float* hbase = sm + L_H + o * 8 * 64;
#pragma unroll 4
      for (int k = 0; k < 64; k += 4) {
        float4 wv = *(const float4*)(wrow + k);        // per-lane row, b128
#pragma unroll
        for (int j = 0; j < 8; ++j) {
          float4 hv = *(const float4*)(hbase + j * 64 + k); // broadcast
          a[j] = fmaf(wv.x, hv.x, a[j]);
          a[j] = fmaf(wv.y, hv.y, a[j]);
          a[j] = fmaf(wv.z, hv.z, a[j]);
          a[j] = fmaf(wv.w, hv.w, a[j]);
        }
      }
      float bb = sm[L_BIN + r];
#pragma unroll
      for (int j = 0; j < 8; ++j)
        sm[L_HP + (o * 8 + j) * 128 + r] = a[j] + bb;  // lanes stride-1: free
    }
    __syncthreads();

    // ---- GEMM2: a[j] = W_rec1[r] . hp[n_j]; tanh; dot with w1/w2; reduce
    {
      float a[8];
#pragma unroll
      for (int j = 0; j < 8; ++j) a[j] = 0.f;
      const float* wrow  = sm + L_WREC + r * 132;
      const float* pbase = sm + L_HP + o * 8 * 128;
#pragma unroll 4
      for (int k = 0; k < 128; k += 4) {
        float4 wv = *(const float4*)(wrow + k);        // per-lane row, b128
#pragma unroll
        for (int j = 0; j < 8; ++j) {
          float4 pv = *(const float4*)(pbase + j * 128 + k); // broadcast
          a[j] = fmaf(wv.x, pv.x, a[j]);
          a[j] = fmaf(wv.y, pv.y, a[j]);
          a[j] = fmaf(wv.z, pv.z, a[j]);
          a[j] = fmaf(wv.w, pv.w, a[j]);
        }
      }
      const float br = sm[L_BREC + r];
      const float q1 = sm[L_V1 + r];
      const float q2 = sm[L_V2 + r];
#pragma unroll
      for (int j = 0; j < 8; ++j) {
        float u  = tanhf(a[j] + br);
        float v1 = q1 * u;
        float v2 = q2 * u;
#pragma unroll
        for (int off = 32; off > 0; off >>= 1) {
          v1 += __shfl_xor(v1, off, 64);
          v2 += __shfl_xor(v2, off, 64);
        }
        if (l == 0) {
          sm[L_RED + (o * 8 + j) * 4 + g * 2 + 0] = v1;
          sm[L_RED + (o * 8 + j) * 4 + g * 2 + 1] = v2;
        }
      }
    }
    __syncthreads();

    // ---- combine row halves, add constants, write d12
    if (t < 128) {
      int j = t >> 1, c = t & 1;
      float d = sm[L_RED + j * 4 + c] + sm[L_RED + j * 4 + 2 + c]
              + (c ? C2 : C1);
      int n = base + j;
      if (n < N_NODES) d12[2 * n + c] = d;
    }
  }
}

// ---------------------------------------------------------------------------
// K3: loss gather + partial reduction. One thread per (s,n) pair.
// ---------------------------------------------------------------------------
__global__ __launch_bounds__(256) void loss_kernel(
    const float* __restrict__ x,
    const int* __restrict__ walks,
    const float* __restrict__ eps,
    const float* ws,
    float* __restrict__ partials) {
  const int idx = blockIdx.x * 256 + threadIdx.x;
  const float sa = ws[WS_SC + 0];
  const float sb = ws[WS_SC + 1];

  float local = 0.f;
  if (idx < S_WALKS * N_NODES) {
    const int j0 = walks[idx * 2];
    const int j1 = walks[idx * 2 + 1];
    const float d1 = ws[WS_D12 + 2 * j0];
    const float d2 = ws[WS_D12 + 2 * j0 + 1];
#pragma unroll
    for (int c = 0; c < 3; ++c) {
      float e  = eps[idx * 3 + c];
      float xt = fmaf(sa, x[j1 * 3 + c], sb * e);
      float diff = fmaf(xt, d1, d2) - e;
      local = fmaf(diff, diff, local);
    }
  }
  for (int off = 32; off > 0; off >>= 1)
    local += __shfl_down(local, off, 64);
  if ((threadIdx.x & 63) == 0)
    partials[blockIdx.x * 4 + (threadIdx.x >> 6)] = local;
}

// ---------------------------------------------------------------------------
// K4: finalize.
// ---------------------------------------------------------------------------
__global__ __launch_bounds__(256) void finalize_kernel(
    const float* __restrict__ partials, int np, float* __restrict__ out) {
  __shared__ float red[256];
  float s = 0.f;
  for (int i = threadIdx.x; i < np; i += 256) s += partials[i];
  red[threadIdx.x] = s;
  __syncthreads();
  for (int w = 128; w > 0; w >>= 1) {
    if (threadIdx.x < w) red[threadIdx.x] += red[threadIdx.x + w];
    __syncthreads();
  }
  if (threadIdx.x == 0)
    out[0] = red[0] * (1.0f / (float)(S_WALKS * N_NODES * 3));
}

// ---------------------------------------------------------------------------
extern "C" void kernel_launch(void* const* d_in, const int* in_sizes, int n_in,
                              void* d_out, int out_size, void* d_ws, size_t ws_size,
                              hipStream_t stream) {
  const float* h      = (const float*)d_in[0];
  const float* x      = (const float*)d_in[1];
  const int*   walks  = (const int*)d_in[2];
  const float* eps    = (const float*)d_in[3];
  const int*   t_idx  = (const int*)d_in[4];
  const float* W_in   = (const float*)d_in[5];
  const float* b_in   = (const float*)d_in[6];
  const float* W_rec  = (const float*)d_in[7];
  const float* b_rec  = (const float*)d_in[8];
  // d_in[9..12] dead (eq_hidden == 0); d_in[15] W_proj dead.
  const float* W_damp = (const float*)d_in[13];
  const float* b_damp = (const float*)d_in[14];
  const float* b_proj = (const float*)d_in[16];

  float* ws  = (float*)d_ws;
  float* out = (float*)d_out;

  // allow >64KB dynamic LDS for the node kernel (154,624 B of 160 KiB max).
  // Host-side attribute set: graph-capture-safe, idempotent.
  (void)hipFuncSetAttribute((const void*)node_kernel,
                            hipFuncAttributeMaxDynamicSharedMemorySize,
                            (int)NODE_LDS_BYTES);

  hipLaunchKernelGGL(precompute_kernel, dim3(1), dim3(128), 0, stream,
                     W_damp, b_damp, b_proj, t_idx, ws);

  hipLaunchKernelGGL(node_kernel, dim3(NODE_GRID), dim3(1024),
                     NODE_LDS_BYTES, stream,
                     h, W_in, b_in, W_rec, b_rec, ws);

  hipLaunchKernelGGL(loss_kernel, dim3(LOSS_BLOCKS), dim3(256), 0, stream,
                     x, walks, eps, ws, ws + WS_PART);

  hipLaunchKernelGGL(finalize_kernel, dim3(1), dim3(256), 0, stream,
                     ws + WS_PART, NPART, out);
}